// Round 1
// baseline (400.385 us; speedup 1.0000x reference)
//
#include <hip/hip_runtime.h>

#define B_ROWS 16384
#define L1DIM  3072
#define NOUT1  16
#define NCOUNT 8
#define CORR   0.9921875f   // 127/128

// ---------------------------------------------------------------------------
// Kernel 1: W1c[s][o][k] = W1_stack[s][o][k] + W1_factor[o][k]
// 8*16*3072 floats = 98304 float4s; grid 384 x 256 exact.
// ---------------------------------------------------------------------------
__global__ void prep_w1(const float* __restrict__ W1_stack,
                        const float* __restrict__ W1_factor,
                        float* __restrict__ W1c) {
    int v = blockIdx.x * 256 + threadIdx.x;        // float4 index
    const float4* S = (const float4*)W1_stack;
    const float4* F = (const float4*)W1_factor;
    float4 a = S[v];
    float4 b = F[v % 12288];                       // 16*3072/4 per stack
    float4 r;
    r.x = a.x + b.x; r.y = a.y + b.y; r.z = a.z + b.z; r.w = a.w + b.w;
    ((float4*)W1c)[v] = r;
}

// ---------------------------------------------------------------------------
// Kernel 2: bucket rows by ls_indices. Single block, 1024 threads.
// offsets[0..8] = exclusive scan of counts; sorted[] = row ids grouped by idx.
// Ballot-aggregated LDS atomics (8 atomics per 64 elements, not per element).
// ---------------------------------------------------------------------------
__global__ void bucket_kernel(const int* __restrict__ ls,
                              int* __restrict__ offsets,
                              int* __restrict__ sorted) {
    __shared__ int tot[NCOUNT];
    __shared__ int cur[NCOUNT];
    int t = threadIdx.x;
    int wv = t >> 6;
    int lane = t & 63;
    if (t < NCOUNT) tot[t] = 0;
    __syncthreads();

    // count
    for (int i0 = wv * 64; i0 < B_ROWS; i0 += 16 * 64) {
        int v = ls[i0 + lane];
        #pragma unroll
        for (int k = 0; k < NCOUNT; ++k) {
            unsigned long long m = __ballot(v == k);
            if (m && lane == 0) atomicAdd(&tot[k], __popcll(m));
        }
    }
    __syncthreads();
    if (t == 0) {
        int run = 0;
        #pragma unroll
        for (int k = 0; k < NCOUNT; ++k) {
            offsets[k] = run; cur[k] = run; run += tot[k];
        }
        offsets[NCOUNT] = run;
    }
    __syncthreads();

    // scatter
    for (int i0 = wv * 64; i0 < B_ROWS; i0 += 16 * 64) {
        int i = i0 + lane;
        int v = ls[i];
        #pragma unroll
        for (int k = 0; k < NCOUNT; ++k) {
            unsigned long long m = __ballot(v == k);
            if (m) {
                int leader = __ffsll((unsigned long long)m) - 1;
                int cnt = __popcll(m);
                int base = 0;
                if (v == k && lane == leader) base = atomicAdd(&cur[k], cnt);
                base = __shfl(base, leader);
                if (v == k) {
                    int rank = __popcll(m & ((1ull << lane) - 1ull));
                    sorted[base + rank] = i;
                }
            }
        }
    }
}

// ---------------------------------------------------------------------------
// Kernel 3: main fused layer-stack kernel.
// Block = 256 threads = 4 waves; each wave owns 8 rows (same bucket).
// Lane (rg,g): rg = lane>>5 picks row-quad, g = lane&31 picks K-stripe.
// Each lane: acc[4 rows][16 outs] over its K-stripe (float4 per iter,
// 128 k per iter, 24 iters). W1c read from L2 (float4, reused x4 rows).
// Reduce-scatter shuffles -> each lane holds full 16-vec of row (g>>3).
// Layers 2+3 computed in-register, one store per row.
// ---------------------------------------------------------------------------
__global__ __launch_bounds__(256, 2)
void ls_main(const float* __restrict__ x,
             const float* __restrict__ W1c,
             const float* __restrict__ b1,
             const float* __restrict__ W2,
             const float* __restrict__ b2,
             const float* __restrict__ W3,
             const float* __restrict__ b3,
             const int* __restrict__ offsets,
             const int* __restrict__ sorted,
             float* __restrict__ out) {
    const int SEGSHIFT = 9;                  // 512 blocks per bucket
    int s   = blockIdx.x >> SEGSHIFT;
    int seg = blockIdx.x & ((1 << SEGSHIFT) - 1);
    int bstart = offsets[s];
    int bend   = offsets[s + 1];
    int start  = bstart + seg * 32;
    if (start >= bend) return;               // empty block, uniform exit

    int tid  = threadIdx.x;
    int wv   = tid >> 6;
    int lane = tid & 63;
    int rg   = lane >> 5;                    // 0..1
    int g    = lane & 31;                    // 0..31  K-stripe

    int rowbase = start + wv * 8 + rg * 4;
    int rid[4];
    const float* xp[4];
    #pragma unroll
    for (int j = 0; j < 4; ++j) {
        int p = rowbase + j;
        int r = (p < bend) ? sorted[p] : 0;  // safe row for OOB lanes
        rid[j] = (p < bend) ? r : -1;
        xp[j]  = x + (size_t)r * L1DIM + g * 4;
    }
    const float* Wp = W1c + (size_t)s * (NOUT1 * L1DIM) + g * 4;

    float acc[4][16];
    #pragma unroll
    for (int j = 0; j < 4; ++j)
        #pragma unroll
        for (int o = 0; o < 16; ++o) acc[j][o] = 0.0f;

    float4 xa[4], xb[4];

    auto LOADX = [&](float4* d, int k) {
        #pragma unroll
        for (int j = 0; j < 4; ++j)
            d[j] = *(const float4*)(xp[j] + k);
    };
    auto FMAB = [&](const float4* xv, int k) {
        #pragma unroll
        for (int o = 0; o < 16; ++o) {
            float4 w4 = *(const float4*)(Wp + o * L1DIM + k);
            #pragma unroll
            for (int j = 0; j < 4; ++j) {
                acc[j][o] = fmaf(xv[j].x, w4.x,
                             fmaf(xv[j].y, w4.y,
                              fmaf(xv[j].z, w4.z,
                               fmaf(xv[j].w, w4.w, acc[j][o]))));
            }
        }
    };

    // K loop: 24 iterations of 128 k, ping-pong x prefetch
    LOADX(xa, 0);
    #pragma unroll 1
    for (int it = 0; it < 24; it += 2) {
        int kB = (it + 1) << 7;
        LOADX(xb, kB);                       // prefetch odd iter
        FMAB(xa, it << 7);
        int kA = (it + 2) << 7;
        if (kA >= L1DIM) kA = 0;             // harmless wrap on last prefetch
        LOADX(xa, kA);
        FMAB(xb, kB);
    }

    // ---- reduce-scatter across the 32 K-stripe lanes ----
    // Step A (xor 16): keep 2 of 4 rows, selected by bit4 of g.
    bool hi4 = (g & 16) != 0;
    float t0[16], t1[16];
    #pragma unroll
    for (int o = 0; o < 16; ++o) {
        float sA = hi4 ? acc[0][o] : acc[2][o];
        float rA = __shfl_xor(sA, 16);
        t0[o] = (hi4 ? acc[2][o] : acc[0][o]) + rA;
        float sB = hi4 ? acc[1][o] : acc[3][o];
        float rB = __shfl_xor(sB, 16);
        t1[o] = (hi4 ? acc[3][o] : acc[1][o]) + rB;
    }
    // Step B (xor 8): keep 1 row, selected by bit3 of g.
    bool hi3 = (g & 8) != 0;
    float r[16];
    #pragma unroll
    for (int o = 0; o < 16; ++o) {
        float sC = hi3 ? t0[o] : t1[o];
        float rC = __shfl_xor(sC, 8);
        r[o] = (hi3 ? t1[o] : t0[o]) + rC;
    }
    // Step C: full butterfly over bits 0..2 (8 lanes now share one row).
    #pragma unroll
    for (int o = 0; o < 16; ++o) {
        r[o] += __shfl_xor(r[o], 4);
        r[o] += __shfl_xor(r[o], 2);
        r[o] += __shfl_xor(r[o], 1);
    }
    int jloc = g >> 3;                       // this lane's row within quad
    int sub  = g & 7;                        // 8 lanes per row

    // ---- epilogue: bias, CReLU^2 concat, layer2 (32x30), layer3 (1x32) ----
    const float* b1p = b1 + s * 16;
    float l1c15 = r[15] + b1p[15];           // l1x_out (not clipped)
    float h[30];
    #pragma unroll
    for (int j = 0; j < 15; ++j) {
        float v = r[j] + b1p[j];
        h[j]      = fminf(v * v * CORR, 1.0f);          // sqr branch, >=0
        h[15 + j] = fminf(fmaxf(v, 0.0f), 1.0f);        // linear branch
    }
    float p3 = 0.0f;
    #pragma unroll
    for (int m = 0; m < 4; ++m) {
        int o2 = sub + m * 8;
        const float2* w2r = (const float2*)(W2 + (size_t)(s * 32 + o2) * 30);
        float a2 = b2[s * 32 + o2];
        #pragma unroll
        for (int jj = 0; jj < 15; ++jj) {
            float2 wv2 = w2r[jj];
            a2 = fmaf(h[2 * jj], wv2.x, fmaf(h[2 * jj + 1], wv2.y, a2));
        }
        a2 = fminf(fmaxf(a2, 0.0f), 1.0f);
        p3 = fmaf(a2, W3[s * 32 + o2], p3);
    }
    p3 += __shfl_xor(p3, 4);
    p3 += __shfl_xor(p3, 2);
    p3 += __shfl_xor(p3, 1);

    if (sub == 0 && rid[jloc] >= 0) {
        out[rid[jloc]] = p3 + b3[s] + l1c15;
    }
}

// ---------------------------------------------------------------------------
extern "C" void kernel_launch(void* const* d_in, const int* in_sizes, int n_in,
                              void* d_out, int out_size, void* d_ws, size_t ws_size,
                              hipStream_t stream) {
    const float* x         = (const float*)d_in[0];
    const int*   ls        = (const int*)  d_in[1];
    const float* W1_stack  = (const float*)d_in[2];
    const float* W1_factor = (const float*)d_in[3];
    const float* b1        = (const float*)d_in[4];
    const float* W2        = (const float*)d_in[5];
    const float* b2        = (const float*)d_in[6];
    const float* W3        = (const float*)d_in[7];
    const float* b3        = (const float*)d_in[8];
    float* out = (float*)d_out;

    char* ws = (char*)d_ws;
    float* W1c    = (float*)ws;                         // 1,572,864 B
    int*   offs   = (int*)(ws + 1572864);               // 9 ints
    int*   sorted = (int*)(ws + 1572864 + 64);          // 65,536 B

    hipLaunchKernelGGL(prep_w1, dim3(384), dim3(256), 0, stream,
                       W1_stack, W1_factor, W1c);
    hipLaunchKernelGGL(bucket_kernel, dim3(1), dim3(1024), 0, stream,
                       ls, offs, sorted);
    hipLaunchKernelGGL(ls_main, dim3(8 * 512), dim3(256), 0, stream,
                       x, W1c, b1, W2, b2, W3, b3, offs, sorted, out);
}

// Round 2
// 362.729 us; speedup vs baseline: 1.1038x; 1.1038x over previous
//
#include <hip/hip_runtime.h>

#define B_ROWS 16384
#define L1DIM  3072
#define NOUT1  16
#define NCOUNT 8
#define CORR   0.9921875f   // 127/128

// ws layout (bytes):
//   partial  @ 0        (32*8*4 = 1024)
//   offsets  @ 1024     (9*4 -> pad 64)
//   cur      @ 1088     (8*4 -> pad 64)
//   W1c      @ 1152     (8*16*3072*4 = 1572864)
//   sorted   @ 1574016  (16384*4 = 65536)
#define WS_PARTIAL 0
#define WS_OFFS    1024
#define WS_CUR     1088
#define WS_W1C     1152
#define WS_SORTED  1574016

// ---------------------------------------------------------------------------
// W1c[s][o][k] = W1_stack[s][o][k] + W1_factor[o][k]
// ---------------------------------------------------------------------------
__global__ void prep_w1(const float* __restrict__ W1_stack,
                        const float* __restrict__ W1_factor,
                        float* __restrict__ W1c) {
    int v = blockIdx.x * 256 + threadIdx.x;        // float4 index
    const float4* S = (const float4*)W1_stack;
    const float4* F = (const float4*)W1_factor;
    float4 a = S[v];
    float4 b = F[v % 12288];                       // 16*3072/4 per stack
    float4 r;
    r.x = a.x + b.x; r.y = a.y + b.y; r.z = a.z + b.z; r.w = a.w + b.w;
    ((float4*)W1c)[v] = r;
}

// ---------------------------------------------------------------------------
// Bucketing, multi-block: count -> scan -> scatter
// ---------------------------------------------------------------------------
__global__ void bucket_count(const int* __restrict__ ls,
                             int* __restrict__ partial) {
    __shared__ int cnt[NCOUNT];
    if (threadIdx.x < NCOUNT) cnt[threadIdx.x] = 0;
    __syncthreads();
    for (int i = blockIdx.x * 256 + threadIdx.x; i < B_ROWS; i += 32 * 256)
        atomicAdd(&cnt[ls[i]], 1);
    __syncthreads();
    if (threadIdx.x < NCOUNT)
        partial[blockIdx.x * NCOUNT + threadIdx.x] = cnt[threadIdx.x];
}

__global__ void bucket_scan(const int* __restrict__ partial,
                            int* __restrict__ offsets,
                            int* __restrict__ cur) {
    __shared__ int tot[NCOUNT];
    int k = threadIdx.x;
    if (k < NCOUNT) {
        int t = 0;
        #pragma unroll
        for (int b = 0; b < 32; ++b) t += partial[b * NCOUNT + k];
        tot[k] = t;
    }
    __syncthreads();
    if (k == 0) {
        int run = 0;
        #pragma unroll
        for (int j = 0; j < NCOUNT; ++j) {
            offsets[j] = run; cur[j] = run; run += tot[j];
        }
        offsets[NCOUNT] = run;
    }
}

__global__ void bucket_scatter(const int* __restrict__ ls,
                               int* __restrict__ cur,
                               int* __restrict__ sorted) {
    int lane = threadIdx.x & 63;
    for (int i = blockIdx.x * 256 + threadIdx.x; i < B_ROWS; i += 32 * 256) {
        int v = ls[i];
        #pragma unroll
        for (int k = 0; k < NCOUNT; ++k) {
            unsigned long long m = __ballot(v == k);
            if (m) {
                int leader = __ffsll((unsigned long long)m) - 1;
                int base = 0;
                if (v == k && lane == leader)
                    base = atomicAdd(&cur[k], __popcll(m));
                base = __shfl(base, leader);
                if (v == k) {
                    int rank = __popcll(m & ((1ull << lane) - 1ull));
                    sorted[base + rank] = i;
                }
            }
        }
    }
}

// ---------------------------------------------------------------------------
// Main fused kernel. Block = 256 thr = 4 waves; wave owns 4 rows (J=2 per
// rg half). Lane (rg = lane>>5, g = lane&31): acc[2][16] over K-stripe g.
// All 16 W float4 loads batched into w[16] per K-step (MLP ~18).
// Reduce-scatter: 16 lanes end up owning one full row 16-vector.
// ---------------------------------------------------------------------------
__global__ __launch_bounds__(256, 3)
void ls_main(const float* __restrict__ x,
             const float* __restrict__ W1c,
             const float* __restrict__ b1,
             const float* __restrict__ W2,
             const float* __restrict__ b2,
             const float* __restrict__ W3,
             const float* __restrict__ b3,
             const int* __restrict__ offsets,
             const int* __restrict__ sorted,
             float* __restrict__ out) {
    const int SEGSHIFT = 10;                 // 1024 segs per bucket (worst case)
    int s   = blockIdx.x >> SEGSHIFT;
    int seg = blockIdx.x & ((1 << SEGSHIFT) - 1);
    int bstart = offsets[s];
    int bend   = offsets[s + 1];
    int start  = bstart + seg * 16;          // 16 rows per block
    if (start >= bend) return;               // uniform early exit

    int tid  = threadIdx.x;
    int wv   = tid >> 6;
    int lane = tid & 63;
    int rg   = lane >> 5;                    // 0..1
    int g    = lane & 31;                    // K-stripe

    int rowbase = start + wv * 4 + rg * 2;   // 2 rows per lane
    int rid[2];
    const float* xp[2];
    #pragma unroll
    for (int j = 0; j < 2; ++j) {
        int p = rowbase + j;
        int r = (p < bend) ? sorted[p] : 0;
        rid[j] = (p < bend) ? r : -1;
        xp[j]  = x + (size_t)r * L1DIM + g * 4;
    }
    const float* Wp = W1c + (size_t)s * (NOUT1 * L1DIM) + g * 4;

    float acc[2][16];
    #pragma unroll
    for (int j = 0; j < 2; ++j)
        #pragma unroll
        for (int o = 0; o < 16; ++o) acc[j][o] = 0.0f;

    float4 xa[2], xb[2];
    auto LOADX = [&](float4* d, int k) {
        #pragma unroll
        for (int j = 0; j < 2; ++j)
            d[j] = *(const float4*)(xp[j] + k);
    };
    auto KITER = [&](const float4* xv, int k) {
        float4 w[16];
        #pragma unroll
        for (int o = 0; o < 16; ++o)
            w[o] = *(const float4*)(Wp + o * L1DIM + k);
        #pragma unroll
        for (int o = 0; o < 16; ++o) {
            #pragma unroll
            for (int j = 0; j < 2; ++j) {
                acc[j][o] = fmaf(xv[j].x, w[o].x,
                             fmaf(xv[j].y, w[o].y,
                              fmaf(xv[j].z, w[o].z,
                               fmaf(xv[j].w, w[o].w, acc[j][o]))));
            }
        }
    };

    LOADX(xa, 0);
    #pragma unroll 1
    for (int it = 0; it < 24; it += 2) {
        int kB = (it + 1) << 7;
        LOADX(xb, kB);
        KITER(xa, it << 7);
        int kA = (it + 2) << 7;
        if (kA >= L1DIM) kA = 0;             // harmless wrap on last prefetch
        LOADX(xa, kA);
        KITER(xb, kB);
    }

    // ---- reduce-scatter within each 32-lane rg group ----
    // Step A (xor 16): lane keeps row j = bit4(g).
    bool hi4 = (g & 16) != 0;
    float r[16];
    #pragma unroll
    for (int o = 0; o < 16; ++o) {
        float sA = hi4 ? acc[0][o] : acc[1][o];   // send the row partner keeps
        float rA = __shfl_xor(sA, 16);
        r[o] = (hi4 ? acc[1][o] : acc[0][o]) + rA;
    }
    // Step B: butterfly over bits 3..0 -> 16 lanes share full row vector.
    #pragma unroll
    for (int o = 0; o < 16; ++o) {
        r[o] += __shfl_xor(r[o], 8);
        r[o] += __shfl_xor(r[o], 4);
        r[o] += __shfl_xor(r[o], 2);
        r[o] += __shfl_xor(r[o], 1);
    }
    int jloc = (g >> 4) & 1;                 // row within this lane's pair
    int sub  = g & 15;                       // 16 lanes per row

    // ---- epilogue: bias, CReLU^2 concat, layer2 (32x30), layer3 (1x32) ----
    const float* b1p = b1 + s * 16;
    float l1c15 = r[15] + b1p[15];           // l1x_out (not clipped)
    float h[30];
    #pragma unroll
    for (int j = 0; j < 15; ++j) {
        float v = r[j] + b1p[j];
        h[j]      = fminf(v * v * CORR, 1.0f);       // sqr branch, >=0
        h[15 + j] = fminf(fmaxf(v, 0.0f), 1.0f);     // linear branch
    }
    float p3 = 0.0f;
    #pragma unroll
    for (int m = 0; m < 2; ++m) {
        int o2 = sub + m * 16;
        const float2* w2r = (const float2*)(W2 + (size_t)(s * 32 + o2) * 30);
        float a2 = b2[s * 32 + o2];
        #pragma unroll
        for (int jj = 0; jj < 15; ++jj) {
            float2 wv2 = w2r[jj];
            a2 = fmaf(h[2 * jj], wv2.x, fmaf(h[2 * jj + 1], wv2.y, a2));
        }
        a2 = fminf(fmaxf(a2, 0.0f), 1.0f);
        p3 = fmaf(a2, W3[s * 32 + o2], p3);
    }
    p3 += __shfl_xor(p3, 8);
    p3 += __shfl_xor(p3, 4);
    p3 += __shfl_xor(p3, 2);
    p3 += __shfl_xor(p3, 1);

    if (sub == 0 && rid[jloc] >= 0) {
        out[rid[jloc]] = p3 + b3[s] + l1c15;
    }
}

// ---------------------------------------------------------------------------
extern "C" void kernel_launch(void* const* d_in, const int* in_sizes, int n_in,
                              void* d_out, int out_size, void* d_ws, size_t ws_size,
                              hipStream_t stream) {
    const float* x         = (const float*)d_in[0];
    const int*   ls        = (const int*)  d_in[1];
    const float* W1_stack  = (const float*)d_in[2];
    const float* W1_factor = (const float*)d_in[3];
    const float* b1        = (const float*)d_in[4];
    const float* W2        = (const float*)d_in[5];
    const float* b2        = (const float*)d_in[6];
    const float* W3        = (const float*)d_in[7];
    const float* b3        = (const float*)d_in[8];
    float* out = (float*)d_out;

    char* ws = (char*)d_ws;
    int*   partial = (int*)(ws + WS_PARTIAL);
    int*   offs    = (int*)(ws + WS_OFFS);
    int*   cur     = (int*)(ws + WS_CUR);
    float* W1c     = (float*)(ws + WS_W1C);
    int*   sorted  = (int*)(ws + WS_SORTED);

    hipLaunchKernelGGL(prep_w1, dim3(384), dim3(256), 0, stream,
                       W1_stack, W1_factor, W1c);
    hipLaunchKernelGGL(bucket_count, dim3(32), dim3(256), 0, stream,
                       ls, partial);
    hipLaunchKernelGGL(bucket_scan, dim3(1), dim3(64), 0, stream,
                       partial, offs, cur);
    hipLaunchKernelGGL(bucket_scatter, dim3(32), dim3(256), 0, stream,
                       ls, cur, sorted);
    hipLaunchKernelGGL(ls_main, dim3(8 << 10), dim3(256), 0, stream,
                       x, W1c, b1, W2, b2, W3, b3, offs, sorted, out);
}

// Round 3
// 352.057 us; speedup vs baseline: 1.1373x; 1.0303x over previous
//
#include <hip/hip_runtime.h>

#define B_ROWS 16384
#define L1DIM  3072
#define NOUT1  16
#define NCOUNT 8
#define CORR   0.9921875f   // 127/128

// ws layout (bytes):
#define WS_PARTIAL 0          // 32*8*4 = 1024
#define WS_OFFS    1024       // 9*4 -> pad 64
#define WS_CUR     1088       // 8*4 -> pad 64
#define WS_W1C     1152       // 8*16*3072*4 = 1572864
#define WS_SORTED  1574016    // 16384*4 = 65536

// ---------------------------------------------------------------------------
// W1c[s][o][k] = W1_stack[s][o][k] + W1_factor[o][k]
// ---------------------------------------------------------------------------
__global__ void prep_w1(const float* __restrict__ W1_stack,
                        const float* __restrict__ W1_factor,
                        float* __restrict__ W1c) {
    int v = blockIdx.x * 256 + threadIdx.x;        // float4 index
    const float4* S = (const float4*)W1_stack;
    const float4* F = (const float4*)W1_factor;
    float4 a = S[v];
    float4 b = F[v % 12288];                       // 16*3072/4 per stack
    float4 r;
    r.x = a.x + b.x; r.y = a.y + b.y; r.z = a.z + b.z; r.w = a.w + b.w;
    ((float4*)W1c)[v] = r;
}

// ---------------------------------------------------------------------------
// Bucketing: count -> scan -> scatter
// ---------------------------------------------------------------------------
__global__ void bucket_count(const int* __restrict__ ls,
                             int* __restrict__ partial) {
    __shared__ int cnt[NCOUNT];
    if (threadIdx.x < NCOUNT) cnt[threadIdx.x] = 0;
    __syncthreads();
    for (int i = blockIdx.x * 256 + threadIdx.x; i < B_ROWS; i += 32 * 256)
        atomicAdd(&cnt[ls[i]], 1);
    __syncthreads();
    if (threadIdx.x < NCOUNT)
        partial[blockIdx.x * NCOUNT + threadIdx.x] = cnt[threadIdx.x];
}

__global__ void bucket_scan(const int* __restrict__ partial,
                            int* __restrict__ offsets,
                            int* __restrict__ cur) {
    __shared__ int tot[NCOUNT];
    int k = threadIdx.x;
    if (k < NCOUNT) {
        int t = 0;
        #pragma unroll
        for (int b = 0; b < 32; ++b) t += partial[b * NCOUNT + k];
        tot[k] = t;
    }
    __syncthreads();
    if (k == 0) {
        int run = 0;
        #pragma unroll
        for (int j = 0; j < NCOUNT; ++j) {
            offsets[j] = run; cur[j] = run; run += tot[j];
        }
        offsets[NCOUNT] = run;
    }
}

__global__ void bucket_scatter(const int* __restrict__ ls,
                               int* __restrict__ cur,
                               int* __restrict__ sorted) {
    int lane = threadIdx.x & 63;
    for (int i = blockIdx.x * 256 + threadIdx.x; i < B_ROWS; i += 32 * 256) {
        int v = ls[i];
        #pragma unroll
        for (int k = 0; k < NCOUNT; ++k) {
            unsigned long long m = __ballot(v == k);
            if (m) {
                int leader = __ffsll((unsigned long long)m) - 1;
                int base = 0;
                if (v == k && lane == leader)
                    base = atomicAdd(&cur[k], __popcll(m));
                base = __shfl(base, leader);
                if (v == k) {
                    int rank = __popcll(m & ((1ull << lane) - 1ull));
                    sorted[base + rank] = i;
                }
            }
        }
    }
}

// ---------------------------------------------------------------------------
// Main fused kernel. Block = 256 thr = 4 waves; 32 rows/block, J=4 rows/lane.
// W chunk (16 outs x 128 k = 8KB) staged in LDS via global_load_lds DMA,
// double-buffered; lanes ds_read_b128 W (conflict-free), x double-buffered
// in registers. One __syncthreads per K-chunk.
// ---------------------------------------------------------------------------
__global__ __launch_bounds__(256, 2)
void ls_main(const float* __restrict__ x,
             const float* __restrict__ W1c,
             const float* __restrict__ b1,
             const float* __restrict__ W2,
             const float* __restrict__ b2,
             const float* __restrict__ W3,
             const float* __restrict__ b3,
             const int* __restrict__ offsets,
             const int* __restrict__ sorted,
             float* __restrict__ out) {
    const int SEGSHIFT = 9;                  // 512 segs per bucket (worst case)
    int s   = blockIdx.x >> SEGSHIFT;
    int seg = blockIdx.x & ((1 << SEGSHIFT) - 1);
    int bstart = offsets[s];
    int bend   = offsets[s + 1];
    int start  = bstart + seg * 32;          // 32 rows per block
    if (start >= bend) return;               // uniform early exit

    __shared__ float wlds[2][NOUT1 * 128];   // 2 x 8KB

    int tid  = threadIdx.x;
    int wv   = tid >> 6;
    int lane = tid & 63;
    int rg   = lane >> 5;                    // 0..1
    int g    = lane & 31;                    // K-stripe
    int gb   = g << 2;                       // float offset of stripe in chunk

    int rowbase = start + wv * 8 + rg * 4;   // 4 rows per lane
    int rid[4];
    const float* xp[4];
    #pragma unroll
    for (int j = 0; j < 4; ++j) {
        int p = rowbase + j;
        int r = (p < bend) ? sorted[p] : 0;
        rid[j] = (p < bend) ? r : -1;
        xp[j]  = x + (size_t)r * L1DIM + gb;
    }
    const float* Ws = W1c + (size_t)s * (NOUT1 * L1DIM);

    float acc[4][16];
    #pragma unroll
    for (int j = 0; j < 4; ++j)
        #pragma unroll
        for (int o = 0; o < 16; ++o) acc[j][o] = 0.0f;

    float4 xa[4], xb[4];
    auto LOADX = [&](float4* d, int k) {
        #pragma unroll
        for (int j = 0; j < 4; ++j)
            d[j] = *(const float4*)(xp[j] + k);
    };

    // Stage 8KB W chunk (o: 0..15, k: kc..kc+127) into wlds[b] via DMA.
    // Each wave issues 2 global_load_lds of 1KB (2 o-rows each).
    auto STAGEW = [&](int b, int kc) {
        #pragma unroll
        for (int q = 0; q < 2; ++q) {
            int opair = (wv << 2) + (q << 1);            // first o of the pair
            int o2    = opair + (lane >> 5);             // this lane's o-row
            const float* src = Ws + (size_t)o2 * L1DIM + kc + ((lane & 31) << 2);
            float* dst = &wlds[b][opair * 128];          // wave-uniform base
            __builtin_amdgcn_global_load_lds(
                (const __attribute__((address_space(1))) void*)src,
                (__attribute__((address_space(3))) void*)dst,
                16, 0, 0);
        }
    };

    auto COMPUTE = [&](int cur, const float4* xv) {
        #pragma unroll
        for (int og = 0; og < 2; ++og) {
            float4 w[8];
            #pragma unroll
            for (int oo = 0; oo < 8; ++oo)
                w[oo] = *(const float4*)&wlds[cur][(og * 8 + oo) * 128 + gb];
            #pragma unroll
            for (int oo = 0; oo < 8; ++oo) {
                int o = og * 8 + oo;
                #pragma unroll
                for (int j = 0; j < 4; ++j) {
                    acc[j][o] = fmaf(xv[j].x, w[oo].x,
                                 fmaf(xv[j].y, w[oo].y,
                                  fmaf(xv[j].z, w[oo].z,
                                   fmaf(xv[j].w, w[oo].w, acc[j][o]))));
                }
            }
        }
    };

    STAGEW(0, 0);
    LOADX(xa, 0);
    __syncthreads();                         // drains DMA (vmcnt0 + barrier)

    #pragma unroll 1
    for (int it = 0; it < 24; it += 2) {
        // even iter: compute buf0/xa, stage chunk it+1 -> buf1, prefetch xb
        int k1 = (it + 1) << 7;
        STAGEW(1, k1);
        LOADX(xb, k1);
        COMPUTE(0, xa);
        __syncthreads();
        // odd iter: compute buf1/xb, stage chunk it+2 -> buf0, prefetch xa
        int k2 = (it + 2) << 7;
        if (it + 2 < 24) { STAGEW(0, k2); LOADX(xa, k2); }
        COMPUTE(1, xb);
        __syncthreads();
    }

    // ---- reduce-scatter across the 32 K-stripe lanes (validated in R0) ----
    bool hi4 = (g & 16) != 0;
    float t0[16], t1[16];
    #pragma unroll
    for (int o = 0; o < 16; ++o) {
        float sA = hi4 ? acc[0][o] : acc[2][o];
        float rA = __shfl_xor(sA, 16);
        t0[o] = (hi4 ? acc[2][o] : acc[0][o]) + rA;
        float sB = hi4 ? acc[1][o] : acc[3][o];
        float rB = __shfl_xor(sB, 16);
        t1[o] = (hi4 ? acc[3][o] : acc[1][o]) + rB;
    }
    bool hi3 = (g & 8) != 0;
    float r[16];
    #pragma unroll
    for (int o = 0; o < 16; ++o) {
        float sC = hi3 ? t0[o] : t1[o];
        float rC = __shfl_xor(sC, 8);
        r[o] = (hi3 ? t1[o] : t0[o]) + rC;
    }
    #pragma unroll
    for (int o = 0; o < 16; ++o) {
        r[o] += __shfl_xor(r[o], 4);
        r[o] += __shfl_xor(r[o], 2);
        r[o] += __shfl_xor(r[o], 1);
    }
    int jloc = g >> 3;                       // row within this lane's quad
    int sub  = g & 7;                        // 8 lanes per row

    // ---- epilogue: bias, CReLU^2 concat, layer2 (32x30), layer3 (1x32) ----
    const float* b1p = b1 + s * 16;
    float l1c15 = r[15] + b1p[15];           // l1x_out (not clipped)
    float h[30];
    #pragma unroll
    for (int j = 0; j < 15; ++j) {
        float v = r[j] + b1p[j];
        h[j]      = fminf(v * v * CORR, 1.0f);       // sqr branch, >=0
        h[15 + j] = fminf(fmaxf(v, 0.0f), 1.0f);     // linear branch
    }
    float p3 = 0.0f;
    #pragma unroll
    for (int m = 0; m < 4; ++m) {
        int o2 = sub + m * 8;
        const float2* w2r = (const float2*)(W2 + (size_t)(s * 32 + o2) * 30);
        float a2 = b2[s * 32 + o2];
        #pragma unroll
        for (int jj = 0; jj < 15; ++jj) {
            float2 wv2 = w2r[jj];
            a2 = fmaf(h[2 * jj], wv2.x, fmaf(h[2 * jj + 1], wv2.y, a2));
        }
        a2 = fminf(fmaxf(a2, 0.0f), 1.0f);
        p3 = fmaf(a2, W3[s * 32 + o2], p3);
    }
    p3 += __shfl_xor(p3, 4);
    p3 += __shfl_xor(p3, 2);
    p3 += __shfl_xor(p3, 1);

    if (sub == 0 && rid[jloc] >= 0) {
        out[rid[jloc]] = p3 + b3[s] + l1c15;
    }
}

// ---------------------------------------------------------------------------
extern "C" void kernel_launch(void* const* d_in, const int* in_sizes, int n_in,
                              void* d_out, int out_size, void* d_ws, size_t ws_size,
                              hipStream_t stream) {
    const float* x         = (const float*)d_in[0];
    const int*   ls        = (const int*)  d_in[1];
    const float* W1_stack  = (const float*)d_in[2];
    const float* W1_factor = (const float*)d_in[3];
    const float* b1        = (const float*)d_in[4];
    const float* W2        = (const float*)d_in[5];
    const float* b2        = (const float*)d_in[6];
    const float* W3        = (const float*)d_in[7];
    const float* b3        = (const float*)d_in[8];
    float* out = (float*)d_out;

    char* ws = (char*)d_ws;
    int*   partial = (int*)(ws + WS_PARTIAL);
    int*   offs    = (int*)(ws + WS_OFFS);
    int*   cur     = (int*)(ws + WS_CUR);
    float* W1c     = (float*)(ws + WS_W1C);
    int*   sorted  = (int*)(ws + WS_SORTED);

    hipLaunchKernelGGL(prep_w1, dim3(384), dim3(256), 0, stream,
                       W1_stack, W1_factor, W1c);
    hipLaunchKernelGGL(bucket_count, dim3(32), dim3(256), 0, stream,
                       ls, partial);
    hipLaunchKernelGGL(bucket_scan, dim3(1), dim3(64), 0, stream,
                       partial, offs, cur);
    hipLaunchKernelGGL(bucket_scatter, dim3(32), dim3(256), 0, stream,
                       ls, cur, sorted);
    hipLaunchKernelGGL(ls_main, dim3(8 << 9), dim3(256), 0, stream,
                       x, W1c, b1, W2, b2, W3, b3, offs, sorted, out);
}